// Round 10
// baseline (172.463 us; speedup 1.0000x reference)
//
#include <hip/hip_runtime.h>
#include <math.h>

#define N_NODES 20000
#define N_EDGES 640000
#define NMAX 8
#define NUM_BASIS 928
#define NRANGE 500        // coarse ranges (bins)
#define RNODES 40         // nodes per range; 500*40 = 20000
#define BINCAP 1792       // records per range bin; mean 1280, +14 sigma
#define TR 72             // f16 LDS row stride (k-dim), 144 B -> bank-spread
#define NBLK 256          // binning blocks
#define CHUNK (N_EDGES / NBLK)          // 2500
#define BINT 512          // threads per binning/compute block (8 waves)
#define RPT 4             // records staged per thread in range_compute (ceil(1792/512))
#define TPB 256
#define WPB 4
#define NPAIRS (N_NODES / 2)
#define SCAN_B 1024
#define SCAN_NB ((N_NODES + SCAN_B - 1) / SCAN_B)   // 20

typedef _Float16 half8 __attribute__((ext_vector_type(8)));
typedef float floatx4 __attribute__((ext_vector_type(4)));

// wave-local LDS sync (guide rule #18)
__device__ __forceinline__ void wsync() {
    asm volatile("s_waitcnt lgkmcnt(0)" ::: "memory");
    __builtin_amdgcn_sched_barrier(0);
}

// ======================= primary: coalesced range-binning =====================
// R0-R9 invariant: ~640K random 64B line-touches cost ~45-50us in any form
// (scattered stores, gathers, fabric atomics). This pipeline has none; R9
// measured 148.2 (first break below the 154-163 band). R10: double
// range_compute occupancy (500 blocks @ 2/CU) + single-read register staging.

// pass 1: per-block histogram over 500 ranges
__global__ __launch_bounds__(BINT) void hist_kernel(
    const int* __restrict__ receivers,
    int* __restrict__ gcounts)           // [NBLK][NRANGE]
{
    __shared__ int h[NRANGE];
    int tid = threadIdx.x, b = blockIdx.x;
    for (int i = tid; i < NRANGE; i += BINT) h[i] = 0;
    __syncthreads();
    int e0 = b * CHUNK;
    for (int i = tid; i < CHUNK; i += BINT)
        atomicAdd(&h[receivers[e0 + i] / RNODES], 1);   // LDS atomic only
    __syncthreads();
    for (int i = tid; i < NRANGE; i += BINT) gcounts[b * NRANGE + i] = h[i];
}

// pass 2: per-range exclusive prefix across blocks (in-place) + totals
__global__ __launch_bounds__(256) void scan_bins(
    int* __restrict__ gcounts,           // in: counts, out: per-block bases
    int* __restrict__ counts)            // [NRANGE] totals
{
    int bin = blockIdx.x * 256 + threadIdx.x;
    if (bin >= NRANGE) return;
    int run = 0;
    for (int b = 0; b < NBLK; ++b) {
        int idx = b * NRANGE + bin;
        int v = gcounts[idx];
        gcounts[idx] = run;
        run += v;
    }
    counts[bin] = run;
}

// pass 3: scatter records into range bins; per (block,bin) writes are
// consecutive slots (~5 per bin per block); zero global atomics.
__global__ __launch_bounds__(BINT) void bin_scatter(
    const float* __restrict__ vectors,
    const int* __restrict__ senders,
    const int* __restrict__ receivers,
    const int* __restrict__ species,
    const int* __restrict__ gbase,       // [NBLK][NRANGE]
    float4* __restrict__ binned)         // [NRANGE][BINCAP]
{
    __shared__ int cur[NRANGE];
    int tid = threadIdx.x, b = blockIdx.x;
    for (int i = tid; i < NRANGE; i += BINT) cur[i] = gbase[b * NRANGE + i];
    __syncthreads();
    int e0 = b * CHUNK;
    for (int i = tid; i < CHUNK; i += BINT) {
        int e = e0 + i;
        int rcv = receivers[e];
        int bin = rcv / RNODES;
        int nl  = rcv - bin * RNODES;                  // 0..39
        int pos = atomicAdd(&cur[bin], 1);             // LDS atomic only
        if (pos < BINCAP) {
            int zs = species[senders[e]];              // 80KB table, L2-hot
            float4 rec;
            rec.x = vectors[3*e+0];
            rec.y = vectors[3*e+1];
            rec.z = vectors[3*e+2];
            rec.w = __int_as_float((zs << 7) | nl);
            binned[(size_t)bin * BINCAP + pos] = rec;
        }
    }
}

// pass 4: one block per range (500 blocks, 2/CU). Single coalesced bin read
// into registers -> LDS counting-sort by node (exact) -> R9-verified per-wave
// pair compute from LDS.
__global__ __launch_bounds__(BINT, 2) void range_compute(
    const float4* __restrict__ binned,
    const int* __restrict__ counts,      // [NRANGE]
    const int* __restrict__ species,
    const float* __restrict__ node_mask,
    const float* __restrict__ wA,
    const float* __restrict__ c_pair,
    const float* __restrict__ c_read,
    const float* __restrict__ E0,
    float* __restrict__ outE,
    float* __restrict__ outB)
{
    __shared__ __align__(16) float4 sRec[BINCAP];               // 28.7 KB
    __shared__ __align__(16) _Float16 sOps[8][2][16 * TR];      // 36.9 KB
    __shared__ int sHist[RNODES];
    __shared__ int sOff[RNODES + 1];
    __shared__ int sCur[RNODES];
    __shared__ float sWA[64];
    __shared__ float sCPall[512];

    int tid = threadIdx.x;
    int w = tid >> 6, lane = tid & 63;
    int row = lane & 15, quad = lane >> 4;
    int r = blockIdx.x;

    if (tid < 64) sWA[tid] = wA[tid];
    if (tid < 256) { sCPall[tid] = c_pair[tid]; sCPall[tid + 256] = c_pair[tid + 256]; }
    for (int i = tid; i < RNODES; i += BINT) sHist[i] = 0;
    __syncthreads();

    int cnt = min(counts[r], BINCAP);
    const float4* src = binned + (size_t)r * BINCAP;

    // single coalesced read into registers (static indices, rule #20)
    float4 reg[RPT];
    #pragma unroll
    for (int k = 0; k < RPT; ++k) {
        int idx = tid + k * BINT;
        if (idx < cnt) reg[k] = src[idx];
    }
    // histogram of node-local ids from registers
    #pragma unroll
    for (int k = 0; k < RPT; ++k) {
        int idx = tid + k * BINT;
        if (idx < cnt) atomicAdd(&sHist[__float_as_int(reg[k].w) & 127], 1);
    }
    __syncthreads();
    if (tid == 0) {                       // 40-entry serial prefix
        int run = 0;
        for (int i = 0; i < RNODES; ++i) { sOff[i] = run; run += sHist[i]; }
        sOff[RNODES] = run;
    }
    __syncthreads();
    for (int i = tid; i < RNODES; i += BINT) sCur[i] = sOff[i];
    __syncthreads();
    // scatter registers into node-grouped LDS layout (order within node
    // irrelevant: segment_sum is order-insensitive up to FP rounding)
    #pragma unroll
    for (int k = 0; k < RPT; ++k) {
        int idx = tid + k * BINT;
        if (idx < cnt) {
            int nl = __float_as_int(reg[k].w) & 127;
            int pos = atomicAdd(&sCur[nl], 1);
            sRec[pos] = reg[k];
        }
    }
    __syncthreads();

    _Float16* sWRT = &sOps[w][0][0];
    _Float16* sYT  = &sOps[w][1][0];

    // 20 pairs / 8 waves
    for (int pi = w; pi < RNODES / 2; pi += 8) {
        wsync();                          // sWRT alias reuse across pairs
        int nl0 = pi * 2, nl1 = nl0 + 1;
        int n0 = r * RNODES + nl0, n1 = n0 + 1;
        int z0 = species[n0], z1 = species[n1];
        int b0 = sOff[nl0], b1 = sOff[nl1];
        int c0 = b1 - b0, c1 = sOff[nl1 + 1] - b1;
        int total = c0 + c1;

        floatx4 acc = {0.0f, 0.0f, 0.0f, 0.0f};
        float ep0 = 0.0f, ep1 = 0.0f;

        for (int base = 0; base < total; base += 64) {
            int j = base + lane;
            bool active = j < total;
            int node = (j >= c0) ? 1 : 0;

            half8 wrh;
            #pragma unroll
            for (int a = 0; a < 8; ++a) wrh[a] = (_Float16)0.0f;
            float Yf[16];
            #pragma unroll
            for (int m = 0; m < 16; ++m) Yf[m] = 0.0f;

            if (active) {
                int jj = node ? (j - c0) : j;
                float4 rec = sRec[(node ? b1 : b0) + jj];   // LDS, grouped
                float vx = rec.x, vy = rec.y, vz = rec.z;
                int zs = __float_as_int(rec.w) >> 7;

                float r2 = vx*vx + vy*vy + vz*vz + 1e-12f;
                float invr = rsqrtf(r2);
                float rr = r2 * invr;
                float dd = rr * 0.2f;                  // r / RCUT
                float d2 = dd*dd, d6 = d2*d2*d2;
                float env = 1.0f + d6 * (-28.0f + 48.0f*dd - 21.0f*d2);
                env = (dd < 1.0f) ? env : 0.0f;
                float pref = 0.6324555320336759f * invr * env;

                float x = 3.14159265358979f * dd;
                float sp = __sinf(x), cp = __cosf(x);
                float twoc = 2.0f * cp;
                float Rn[NMAX];
                float s_prev = 0.0f, s_cur = sp;
                Rn[0] = pref * s_cur;
                #pragma unroll
                for (int nq = 1; nq < NMAX; ++nq) {
                    float s_next = twoc * s_cur - s_prev;
                    s_prev = s_cur; s_cur = s_next;
                    Rn[nq] = pref * s_cur;
                }

                int zr = node ? z1 : z0;
                float ep = 0.0f;
                #pragma unroll
                for (int nq = 0; nq < NMAX; ++nq) ep += sCPall[(zr*8 + zs)*8 + nq] * Rn[nq];
                if (node) ep1 += 0.5f * ep; else ep0 += 0.5f * ep;

                #pragma unroll
                for (int a = 0; a < NMAX; ++a) wrh[a] = (_Float16)(sWA[zs*8+a] * Rn[a]);

                float ux = vx*invr, uy = vy*invr, uz = vz*invr;
                float xx = ux*ux, yy = uy*uy, zz = uz*uz;
                Yf[0]  = 0.28209479177387814f;
                Yf[1]  = 0.4886025119029199f  * uy;
                Yf[2]  = 0.4886025119029199f  * uz;
                Yf[3]  = 0.4886025119029199f  * ux;
                Yf[4]  = 1.0925484305920792f  * ux * uy;
                Yf[5]  = 1.0925484305920792f  * uy * uz;
                Yf[6]  = 0.31539156525252005f * (3.0f*zz - 1.0f);
                Yf[7]  = 1.0925484305920792f  * ux * uz;
                Yf[8]  = 0.5462742152960396f  * (xx - yy);
                Yf[9]  = 0.5900435899266435f  * uy * (3.0f*xx - yy);
                Yf[10] = 2.890611442640554f   * ux * uy * uz;
                Yf[11] = 0.4570457994644658f  * uy * (5.0f*zz - 1.0f);
                Yf[12] = 0.3731763325901154f  * uz * (5.0f*zz - 3.0f);
                Yf[13] = 0.4570457994644658f  * ux * (5.0f*zz - 1.0f);
                Yf[14] = 1.445305721320277f   * uz * (xx - yy);
                Yf[15] = 0.5900435899266435f  * ux * (xx - 3.0f*yy);
            }

            int rb = node * 8;
            #pragma unroll
            for (int a = 0; a < 8; ++a) {
                sWRT[(rb + a) * TR + lane]       = wrh[a];
                sWRT[((rb ^ 8) + a) * TR + lane] = (_Float16)0.0f;
            }
            #pragma unroll
            for (int m = 0; m < 16; ++m) sYT[m * TR + lane] = (_Float16)Yf[m];
            wsync();

            acc = __builtin_amdgcn_mfma_f32_16x16x32_f16(
                *(const half8*)&sWRT[row * TR + quad * 8],
                *(const half8*)&sYT [row * TR + quad * 8], acc, 0, 0, 0);
            if (total - base > 32)
                acc = __builtin_amdgcn_mfma_f32_16x16x32_f16(
                    *(const half8*)&sWRT[row * TR + 32 + quad * 8],
                    *(const half8*)&sYT [row * TR + 32 + quad * 8], acc, 0, 0, 0);
            wsync();
        }

        // epilogue scratch aliases the dead MFMA operand region (per-wave)
        float* sA = (float*)sWRT;
        float* sP = sA + 256;

        #pragma unroll
        for (int rg = 0; rg < 4; ++rg)
            sA[(quad * 4 + rg) * 16 + row] = acc[rg];
        wsync();

        {   // P: all 64 lanes, one (node,a,l) each
            int nd = lane >> 5, a = (lane >> 2) & 7, l = lane & 3;
            int arow = nd * 8 + a;
            int m0 = l * l, m1 = (l + 1) * (l + 1);
            float s = 0.0f;
            for (int m = m0; m < m1; ++m) { float vv = sA[arow * 16 + m]; s += vv * vv; }
            sP[nd * 32 + a * 4 + l] = s;
        }
        wsync();

        int nd = lane >> 5, l32 = lane & 31;
        int n = nd ? n1 : n0;
        int z = nd ? z1 : z0;
        const float* sPn = sP + nd * 32;
        const floatx4* cr4 = (const floatx4*)(c_read + (size_t)z * NUM_BASIS);
        floatx4* Brow4 = (floatx4*)(outB + (size_t)n * NUM_BASIS);
        float Ep = 0.0f;
        #pragma unroll
        for (int it = 0; it < 8; ++it) {
            int fi = l32 + it * 32;
            if (fi < 232) {
                floatx4 B;
                if (fi < 8) {
                    B = *(const floatx4*)&sPn[fi * 4];
                } else {
                    int t = fi - 8;
                    int k = t % 7;
                    int t2 = t / 7;
                    int l = t2 & 3, a = t2 >> 2;
                    int o = k + (k >= a ? 1 : 0);
                    float pp = sPn[a * 4 + l];
                    floatx4 po = *(const floatx4*)&sPn[o * 4];
                    B = pp * po;
                }
                __builtin_nontemporal_store(B, &Brow4[fi]);
                floatx4 c = cr4[fi];
                Ep += B[0]*c[0] + B[1]*c[1] + B[2]*c[2] + B[3]*c[3];
            }
        }
        #pragma unroll
        for (int off = 16; off > 0; off >>= 1) Ep += __shfl_down(Ep, off);
        #pragma unroll
        for (int off = 1; off < 64; off <<= 1) {
            ep0 += __shfl_xor(ep0, off);
            ep1 += __shfl_xor(ep1, off);
        }
        if (l32 == 0) {
            float epv = nd ? ep1 : ep0;
            outE[n] = (Ep + epv + E0[z]) * node_mask[n];
        }
    }
}

// ===================== fallback path: exact CSR (unchanged) ==================
__global__ __launch_bounds__(256) void count_kernel(const int* __restrict__ receivers,
                                                    int* __restrict__ counts) {
    int e = blockIdx.x * blockDim.x + threadIdx.x;
    if (e < N_EDGES) atomicAdd(&counts[receivers[e]], 1);
}

__global__ __launch_bounds__(SCAN_B) void scan_blocks(const int* __restrict__ counts,
                                                      int* __restrict__ prefix,
                                                      int* __restrict__ blockSums) {
    int tid = threadIdx.x;
    int gid = blockIdx.x * SCAN_B + tid;
    int c = (gid < N_NODES) ? counts[gid] : 0;
    int lane = tid & 63, wave = tid >> 6;
    int s = c;
    #pragma unroll
    for (int off = 1; off < 64; off <<= 1) {
        int v = __shfl_up(s, off);
        if (lane >= off) s += v;
    }
    __shared__ int waveTot[16];
    __shared__ int waveExcl[16];
    if (lane == 63) waveTot[wave] = s;
    __syncthreads();
    if (tid == 0) {
        int run = 0;
        #pragma unroll
        for (int ww = 0; ww < 16; ++ww) { waveExcl[ww] = run; run += waveTot[ww]; }
        blockSums[blockIdx.x] = run;
    }
    __syncthreads();
    int excl = (s - c) + waveExcl[wave];
    if (gid < N_NODES) prefix[gid] = excl;
}

__global__ __launch_bounds__(SCAN_B) void scan_finalize(const int* __restrict__ prefix,
                                                        const int* __restrict__ blockSums,
                                                        int* __restrict__ offsets,
                                                        int* __restrict__ cursors) {
    __shared__ int blockOff;
    int tid = threadIdx.x;
    if (tid == 0) {
        int run = 0;
        for (int b = 0; b < blockIdx.x; ++b) run += blockSums[b];
        blockOff = run;
    }
    __syncthreads();
    int gid = blockIdx.x * SCAN_B + tid;
    if (gid < N_NODES) {
        int v = prefix[gid] + blockOff;
        offsets[gid] = v;
        cursors[gid] = v;
    }
}

__global__ __launch_bounds__(256) void scatter_rec_kernel(
    const float* __restrict__ vectors,
    const int* __restrict__ senders,
    const int* __restrict__ receivers,
    const int* __restrict__ species,
    int* __restrict__ cursors,
    float4* __restrict__ feat)
{
    int e = blockIdx.x * 256 + threadIdx.x;
    if (e >= N_EDGES) return;
    int rcv = receivers[e];
    int pos = atomicAdd(&cursors[rcv], 1);
    float4 rec;
    rec.x = vectors[3*e+0];
    rec.y = vectors[3*e+1];
    rec.z = vectors[3*e+2];
    rec.w = __int_as_float(species[senders[e]]);
    feat[pos] = rec;
}

// CSR-consuming node kernel (R7-verified), fallback only
__global__ __launch_bounds__(TPB, 5) void ace_node_csr(
    const float4* __restrict__ feat,
    const int* __restrict__ counts,
    const int* __restrict__ offsets,
    const int* __restrict__ species,
    const float* __restrict__ node_mask,
    const float* __restrict__ wA,
    const float* __restrict__ c_pair,
    const float* __restrict__ c_read,
    const float* __restrict__ E0,
    float* __restrict__ outE,
    float* __restrict__ outB)
{
    int tid = threadIdx.x;
    int w = tid >> 6, lane = tid & 63;
    int row = lane & 15, quad = lane >> 4;

    __shared__ __align__(16) _Float16 sOps[WPB][2][16 * TR];
    __shared__ float sWA[64];
    __shared__ float sCPall[512];

    if (tid < 64) sWA[tid] = wA[tid];
    sCPall[tid]       = c_pair[tid];
    sCPall[tid + 256] = c_pair[tid + 256];
    __syncthreads();

    _Float16* sWRT = &sOps[w][0][0];
    _Float16* sYT  = &sOps[w][1][0];

    int p = blockIdx.x * WPB + w;
    if (p >= NPAIRS) return;
    int n0 = p * 2, n1 = n0 + 1;
    int z0 = species[n0], z1 = species[n1];

    int c0 = counts[n0], c1 = counts[n1];
    size_t base0 = (size_t)offsets[n0], base1 = (size_t)offsets[n1];
    int total = c0 + c1;

    floatx4 acc = {0.0f, 0.0f, 0.0f, 0.0f};
    float ep0 = 0.0f, ep1 = 0.0f;

    for (int base = 0; base < total; base += 64) {
        int j = base + lane;
        bool active = j < total;
        int node = (j >= c0) ? 1 : 0;

        half8 wrh;
        #pragma unroll
        for (int a = 0; a < 8; ++a) wrh[a] = (_Float16)0.0f;
        float Yf[16];
        #pragma unroll
        for (int m = 0; m < 16; ++m) Yf[m] = 0.0f;

        if (active) {
            int jj = node ? (j - c0) : j;
            float4 rec = feat[(node ? base1 : base0) + jj];
            float vx = rec.x, vy = rec.y, vz = rec.z;
            int zs = __float_as_int(rec.w);

            float r2 = vx*vx + vy*vy + vz*vz + 1e-12f;
            float invr = rsqrtf(r2);
            float rr = r2 * invr;
            float dd = rr * 0.2f;
            float d2 = dd*dd, d6 = d2*d2*d2;
            float env = 1.0f + d6 * (-28.0f + 48.0f*dd - 21.0f*d2);
            env = (dd < 1.0f) ? env : 0.0f;
            float pref = 0.6324555320336759f * invr * env;

            float x = 3.14159265358979f * dd;
            float sp = __sinf(x), cp = __cosf(x);
            float twoc = 2.0f * cp;
            float Rn[NMAX];
            float s_prev = 0.0f, s_cur = sp;
            Rn[0] = pref * s_cur;
            #pragma unroll
            for (int nq = 1; nq < NMAX; ++nq) {
                float s_next = twoc * s_cur - s_prev;
                s_prev = s_cur; s_cur = s_next;
                Rn[nq] = pref * s_cur;
            }

            int zr = node ? z1 : z0;
            float ep = 0.0f;
            #pragma unroll
            for (int nq = 0; nq < NMAX; ++nq) ep += sCPall[(zr*8 + zs)*8 + nq] * Rn[nq];
            if (node) ep1 += 0.5f * ep; else ep0 += 0.5f * ep;

            #pragma unroll
            for (int a = 0; a < NMAX; ++a) wrh[a] = (_Float16)(sWA[zs*8+a] * Rn[a]);

            float ux = vx*invr, uy = vy*invr, uz = vz*invr;
            float xx = ux*ux, yy = uy*uy, zz = uz*uz;
            Yf[0]  = 0.28209479177387814f;
            Yf[1]  = 0.4886025119029199f  * uy;
            Yf[2]  = 0.4886025119029199f  * uz;
            Yf[3]  = 0.4886025119029199f  * ux;
            Yf[4]  = 1.0925484305920792f  * ux * uy;
            Yf[5]  = 1.0925484305920792f  * uy * uz;
            Yf[6]  = 0.31539156525252005f * (3.0f*zz - 1.0f);
            Yf[7]  = 1.0925484305920792f  * ux * uz;
            Yf[8]  = 0.5462742152960396f  * (xx - yy);
            Yf[9]  = 0.5900435899266435f  * uy * (3.0f*xx - yy);
            Yf[10] = 2.890611442640554f   * ux * uy * uz;
            Yf[11] = 0.4570457994644658f  * uy * (5.0f*zz - 1.0f);
            Yf[12] = 0.3731763325901154f  * uz * (5.0f*zz - 3.0f);
            Yf[13] = 0.4570457994644658f  * ux * (5.0f*zz - 1.0f);
            Yf[14] = 1.445305721320277f   * uz * (xx - yy);
            Yf[15] = 0.5900435899266435f  * ux * (xx - 3.0f*yy);
        }

        int rb = node * 8;
        #pragma unroll
        for (int a = 0; a < 8; ++a) {
            sWRT[(rb + a) * TR + lane]       = wrh[a];
            sWRT[((rb ^ 8) + a) * TR + lane] = (_Float16)0.0f;
        }
        #pragma unroll
        for (int m = 0; m < 16; ++m) sYT[m * TR + lane] = (_Float16)Yf[m];
        wsync();

        acc = __builtin_amdgcn_mfma_f32_16x16x32_f16(
            *(const half8*)&sWRT[row * TR + quad * 8],
            *(const half8*)&sYT [row * TR + quad * 8], acc, 0, 0, 0);
        if (total - base > 32)
            acc = __builtin_amdgcn_mfma_f32_16x16x32_f16(
                *(const half8*)&sWRT[row * TR + 32 + quad * 8],
                *(const half8*)&sYT [row * TR + 32 + quad * 8], acc, 0, 0, 0);
        wsync();
    }

    float* sA = (float*)sWRT;
    float* sP = sA + 256;

    #pragma unroll
    for (int rg = 0; rg < 4; ++rg)
        sA[(quad * 4 + rg) * 16 + row] = acc[rg];
    wsync();

    {
        int nd = lane >> 5, a = (lane >> 2) & 7, l = lane & 3;
        int arow = nd * 8 + a;
        int m0 = l * l, m1 = (l + 1) * (l + 1);
        float s = 0.0f;
        for (int m = m0; m < m1; ++m) { float vv = sA[arow * 16 + m]; s += vv * vv; }
        sP[nd * 32 + a * 4 + l] = s;
    }
    wsync();

    int nd = lane >> 5, l32 = lane & 31;
    int n = nd ? n1 : n0;
    int z = nd ? z1 : z0;
    const float* sPn = sP + nd * 32;
    const floatx4* cr4 = (const floatx4*)(c_read + (size_t)z * NUM_BASIS);
    floatx4* Brow4 = (floatx4*)(outB + (size_t)n * NUM_BASIS);
    float Ep = 0.0f;
    #pragma unroll
    for (int it = 0; it < 8; ++it) {
        int fi = l32 + it * 32;
        if (fi < 232) {
            floatx4 B;
            if (fi < 8) {
                B = *(const floatx4*)&sPn[fi * 4];
            } else {
                int t = fi - 8;
                int k = t % 7;
                int t2 = t / 7;
                int l = t2 & 3, a = t2 >> 2;
                int o = k + (k >= a ? 1 : 0);
                float pp = sPn[a * 4 + l];
                floatx4 po = *(const floatx4*)&sPn[o * 4];
                B = pp * po;
            }
            __builtin_nontemporal_store(B, &Brow4[fi]);
            floatx4 c = cr4[fi];
            Ep += B[0]*c[0] + B[1]*c[1] + B[2]*c[2] + B[3]*c[3];
        }
    }
    #pragma unroll
    for (int off = 16; off > 0; off >>= 1) Ep += __shfl_down(Ep, off);
    #pragma unroll
    for (int off = 1; off < 64; off <<= 1) {
        ep0 += __shfl_xor(ep0, off);
        ep1 += __shfl_xor(ep1, off);
    }
    if (l32 == 0) {
        float epv = nd ? ep1 : ep0;
        outE[n] = (Ep + epv + E0[z]) * node_mask[n];
    }
}

extern "C" void kernel_launch(void* const* d_in, const int* in_sizes, int n_in,
                              void* d_out, int out_size, void* d_ws, size_t ws_size,
                              hipStream_t stream) {
    const float* vectors   = (const float*)d_in[0];
    const int*   senders   = (const int*)d_in[1];
    const int*   receivers = (const int*)d_in[2];
    const int*   species   = (const int*)d_in[3];
    const float* node_mask = (const float*)d_in[4];
    const float* wA        = (const float*)d_in[5];
    const float* c_read    = (const float*)d_in[6];
    const float* E0        = (const float*)d_in[7];
    const float* c_pair    = (const float*)d_in[8];

    float* outE = (float*)d_out;        // [20000]
    float* outB = outE + N_NODES;       // [20000][928]

    size_t binnedBytes = (size_t)NRANGE * BINCAP * sizeof(float4);           // 14.34 MB
    size_t gcountBytes = (size_t)NBLK * NRANGE * sizeof(int);                // 512 KB
    size_t countBytes  = (size_t)NRANGE * sizeof(int);                       // 2 KB
    size_t primaryNeed = binnedBytes + gcountBytes + countBytes;             // ~14.9 MB

    if (ws_size >= primaryNeed) {
        // ---- primary: 4 dispatches, no memset, no global atomics,
        //      no random 64B line-touches ----
        float4* binned = (float4*)d_ws;
        int* gcounts   = (int*)((char*)d_ws + binnedBytes);
        int* counts    = (int*)((char*)d_ws + binnedBytes + gcountBytes);
        hist_kernel<<<NBLK, BINT, 0, stream>>>(receivers, gcounts);
        scan_bins<<<(NRANGE + 255)/256, 256, 0, stream>>>(gcounts, counts);
        bin_scatter<<<NBLK, BINT, 0, stream>>>(
            vectors, senders, receivers, species, gcounts, binned);
        range_compute<<<NRANGE, BINT, 0, stream>>>(
            binned, counts, species, node_mask, wA, c_pair, c_read, E0, outE, outB);
    } else {
        // ---- fallback: exact CSR of records (10.24 MB + scan arrays) ----
        float4* feat   = (float4*)d_ws;                    // 640000 recs
        int* counts    = (int*)((char*)d_ws + (size_t)N_EDGES * sizeof(float4));
        int* offsets   = counts + N_NODES;
        int* cursors   = offsets + N_NODES;
        int* prefix    = cursors + N_NODES;
        int* blockSums = prefix + N_NODES;
        hipMemsetAsync(counts, 0, N_NODES * sizeof(int), stream);
        count_kernel<<<(N_EDGES + 255)/256, 256, 0, stream>>>(receivers, counts);
        scan_blocks<<<SCAN_NB, SCAN_B, 0, stream>>>(counts, prefix, blockSums);
        scan_finalize<<<SCAN_NB, SCAN_B, 0, stream>>>(prefix, blockSums, offsets, cursors);
        scatter_rec_kernel<<<(N_EDGES + 255)/256, 256, 0, stream>>>(
            vectors, senders, receivers, species, cursors, feat);
        ace_node_csr<<<(NPAIRS + WPB - 1)/WPB, TPB, 0, stream>>>(
            feat, counts, offsets, species, node_mask,
            wA, c_pair, c_read, E0, outE, outB);
    }
}

// Round 11
// 139.475 us; speedup vs baseline: 1.2365x; 1.2365x over previous
//
#include <hip/hip_runtime.h>
#include <math.h>

#define N_NODES 20000
#define N_EDGES 640000
#define NMAX 8
#define NUM_BASIS 928
#define NRANGE 250        // coarse ranges (bins)
#define RNODES 80         // nodes per range; 250*80 = 20000
#define BINCAP 3072       // records per range bin; mean 2560, +10 sigma
#define TR 72             // f16 LDS row stride (k-dim), 144 B -> bank-spread
#define NBLK 256          // binning blocks
#define CHUNK (N_EDGES / NBLK)          // 2500
#define BINT 512          // threads per binning/compute block (8 waves)
#define TPB 256
#define WPB 4
#define NPAIRS (N_NODES / 2)
#define SCAN_B 1024
#define SCAN_NB ((N_NODES + SCAN_B - 1) / SCAN_B)   // 20

typedef _Float16 half8 __attribute__((ext_vector_type(8)));
typedef float floatx4 __attribute__((ext_vector_type(4)));

// wave-local LDS sync (guide rule #18)
__device__ __forceinline__ void wsync() {
    asm volatile("s_waitcnt lgkmcnt(0)" ::: "memory");
    __builtin_amdgcn_sched_barrier(0);
}

// ======================= primary: coalesced range-binning =====================
// R0-R9 invariant: ~640K random 64B line-touches cost ~45-50us in any form.
// This pipeline has none; R9 measured 148.2us. R10's launch_bounds(512,2)
// regression (VGPR cap -> spills) REVERTED. R11: only scan_bins parallelized
// (1 block / 4 waves -> 252 waves, one per bin).

// pass 1: per-block histogram over 250 ranges
__global__ __launch_bounds__(BINT) void hist_kernel(
    const int* __restrict__ receivers,
    int* __restrict__ gcounts)           // [NBLK][NRANGE]
{
    __shared__ int h[NRANGE];
    int tid = threadIdx.x, b = blockIdx.x;
    for (int i = tid; i < NRANGE; i += BINT) h[i] = 0;
    __syncthreads();
    int e0 = b * CHUNK;
    for (int i = tid; i < CHUNK; i += BINT)
        atomicAdd(&h[receivers[e0 + i] / RNODES], 1);   // LDS atomic only
    __syncthreads();
    for (int i = tid; i < NRANGE; i += BINT) gcounts[b * NRANGE + i] = h[i];
}

// pass 2: per-bin exclusive prefix across the 256 blocks — ONE WAVE PER BIN.
// Lane l owns block-slots {l, l+64, l+128, l+192}; total order = (lane, k).
// Any fixed block order is valid: sub-segments only need to tile [0,total),
// and record order within a node is FP-order-insensitive (as with atomics).
__global__ __launch_bounds__(256) void scan_bins(
    int* __restrict__ gcounts,           // in: counts, out: per-block bases
    int* __restrict__ counts)            // [NRANGE] totals
{
    int wv = blockIdx.x * 4 + (threadIdx.x >> 6);   // bin id
    int lane = threadIdx.x & 63;
    if (wv >= NRANGE) return;
    int v0 = gcounts[(lane)       * NRANGE + wv];
    int v1 = gcounts[(lane +  64) * NRANGE + wv];
    int v2 = gcounts[(lane + 128) * NRANGE + wv];
    int v3 = gcounts[(lane + 192) * NRANGE + wv];
    int s = v0 + v1 + v2 + v3;
    int run = s;
    #pragma unroll
    for (int off = 1; off < 64; off <<= 1) {
        int t = __shfl_up(run, off);
        if (lane >= off) run += t;
    }
    int base = run - s;                  // exclusive prefix of lane sums
    gcounts[(lane)       * NRANGE + wv] = base;  base += v0;
    gcounts[(lane +  64) * NRANGE + wv] = base;  base += v1;
    gcounts[(lane + 128) * NRANGE + wv] = base;  base += v2;
    gcounts[(lane + 192) * NRANGE + wv] = base;  base += v3;
    if (lane == 63) counts[wv] = base;   // grand total for this bin
}

// pass 3: scatter records into range bins; per (block,bin) writes are
// consecutive slots (~10 per bin per block); zero global atomics.
__global__ __launch_bounds__(BINT) void bin_scatter(
    const float* __restrict__ vectors,
    const int* __restrict__ senders,
    const int* __restrict__ receivers,
    const int* __restrict__ species,
    const int* __restrict__ gbase,       // [NBLK][NRANGE]
    float4* __restrict__ binned)         // [NRANGE][BINCAP]
{
    __shared__ int cur[NRANGE];
    int tid = threadIdx.x, b = blockIdx.x;
    for (int i = tid; i < NRANGE; i += BINT) cur[i] = gbase[b * NRANGE + i];
    __syncthreads();
    int e0 = b * CHUNK;
    for (int i = tid; i < CHUNK; i += BINT) {
        int e = e0 + i;
        int rcv = receivers[e];
        int bin = rcv / RNODES;
        int nl  = rcv - bin * RNODES;                  // 0..79
        int pos = atomicAdd(&cur[bin], 1);             // LDS atomic only
        if (pos < BINCAP) {
            int zs = species[senders[e]];              // 80KB table, L2-hot
            float4 rec;
            rec.x = vectors[3*e+0];
            rec.y = vectors[3*e+1];
            rec.z = vectors[3*e+2];
            rec.w = __int_as_float((zs << 7) | nl);
            binned[(size_t)bin * BINCAP + pos] = rec;
        }
    }
}

// pass 4: one block per range. Contiguous bin read -> LDS counting-sort by
// node (exact, no drops) -> R9-verified per-wave pair compute from LDS.
// launch_bounds(BINT,1): do NOT cap registers (R10 lesson: (BINT,2) spills).
__global__ __launch_bounds__(BINT, 1) void range_compute(
    const float4* __restrict__ binned,
    const int* __restrict__ counts,      // [NRANGE]
    const int* __restrict__ species,
    const float* __restrict__ node_mask,
    const float* __restrict__ wA,
    const float* __restrict__ c_pair,
    const float* __restrict__ c_read,
    const float* __restrict__ E0,
    float* __restrict__ outE,
    float* __restrict__ outB)
{
    __shared__ __align__(16) float4 sRec[BINCAP];               // 48 KB
    __shared__ __align__(16) _Float16 sOps[8][2][16 * TR];      // 36.9 KB
    __shared__ int sHist[RNODES];
    __shared__ int sOff[RNODES + 1];
    __shared__ int sCur[RNODES];
    __shared__ float sWA[64];
    __shared__ float sCPall[512];

    int tid = threadIdx.x;
    int w = tid >> 6, lane = tid & 63;
    int row = lane & 15, quad = lane >> 4;
    int r = blockIdx.x;

    if (tid < 64) sWA[tid] = wA[tid];
    if (tid < 256) { sCPall[tid] = c_pair[tid]; sCPall[tid + 256] = c_pair[tid + 256]; }
    for (int i = tid; i < RNODES; i += BINT) sHist[i] = 0;
    __syncthreads();

    int cnt = min(counts[r], BINCAP);
    const float4* src = binned + (size_t)r * BINCAP;

    // histogram of node-local ids
    for (int i = tid; i < cnt; i += BINT) {
        int wv = __float_as_int(src[i].w);
        atomicAdd(&sHist[wv & 127], 1);
    }
    __syncthreads();
    if (tid == 0) {                       // 80-entry serial prefix
        int run = 0;
        for (int i = 0; i < RNODES; ++i) { sOff[i] = run; run += sHist[i]; }
        sOff[RNODES] = run;
    }
    __syncthreads();
    for (int i = tid; i < RNODES; i += BINT) sCur[i] = sOff[i];
    __syncthreads();
    // scatter into node-grouped LDS layout (second read is L2-hot; order
    // within node irrelevant: segment_sum is order-insensitive up to FP)
    for (int i = tid; i < cnt; i += BINT) {
        float4 rec = src[i];
        int nl = __float_as_int(rec.w) & 127;
        int pos = atomicAdd(&sCur[nl], 1);
        sRec[pos] = rec;
    }
    __syncthreads();

    _Float16* sWRT = &sOps[w][0][0];
    _Float16* sYT  = &sOps[w][1][0];

    // 40 pairs / 8 waves = 5 sequential pairs per wave
    for (int pi = w; pi < RNODES / 2; pi += 8) {
        wsync();                          // sWRT alias reuse across pairs
        int nl0 = pi * 2, nl1 = nl0 + 1;
        int n0 = r * RNODES + nl0, n1 = n0 + 1;
        int z0 = species[n0], z1 = species[n1];
        int b0 = sOff[nl0], b1 = sOff[nl1];
        int c0 = b1 - b0, c1 = sOff[nl1 + 1] - b1;
        int total = c0 + c1;

        floatx4 acc = {0.0f, 0.0f, 0.0f, 0.0f};
        float ep0 = 0.0f, ep1 = 0.0f;

        for (int base = 0; base < total; base += 64) {
            int j = base + lane;
            bool active = j < total;
            int node = (j >= c0) ? 1 : 0;

            half8 wrh;
            #pragma unroll
            for (int a = 0; a < 8; ++a) wrh[a] = (_Float16)0.0f;
            float Yf[16];
            #pragma unroll
            for (int m = 0; m < 16; ++m) Yf[m] = 0.0f;

            if (active) {
                int jj = node ? (j - c0) : j;
                float4 rec = sRec[(node ? b1 : b0) + jj];   // LDS, grouped
                float vx = rec.x, vy = rec.y, vz = rec.z;
                int zs = __float_as_int(rec.w) >> 7;

                float r2 = vx*vx + vy*vy + vz*vz + 1e-12f;
                float invr = rsqrtf(r2);
                float rr = r2 * invr;
                float dd = rr * 0.2f;                  // r / RCUT
                float d2 = dd*dd, d6 = d2*d2*d2;
                float env = 1.0f + d6 * (-28.0f + 48.0f*dd - 21.0f*d2);
                env = (dd < 1.0f) ? env : 0.0f;
                float pref = 0.6324555320336759f * invr * env;

                float x = 3.14159265358979f * dd;
                float sp = __sinf(x), cp = __cosf(x);
                float twoc = 2.0f * cp;
                float Rn[NMAX];
                float s_prev = 0.0f, s_cur = sp;
                Rn[0] = pref * s_cur;
                #pragma unroll
                for (int nq = 1; nq < NMAX; ++nq) {
                    float s_next = twoc * s_cur - s_prev;
                    s_prev = s_cur; s_cur = s_next;
                    Rn[nq] = pref * s_cur;
                }

                int zr = node ? z1 : z0;
                float ep = 0.0f;
                #pragma unroll
                for (int nq = 0; nq < NMAX; ++nq) ep += sCPall[(zr*8 + zs)*8 + nq] * Rn[nq];
                if (node) ep1 += 0.5f * ep; else ep0 += 0.5f * ep;

                #pragma unroll
                for (int a = 0; a < NMAX; ++a) wrh[a] = (_Float16)(sWA[zs*8+a] * Rn[a]);

                float ux = vx*invr, uy = vy*invr, uz = vz*invr;
                float xx = ux*ux, yy = uy*uy, zz = uz*uz;
                Yf[0]  = 0.28209479177387814f;
                Yf[1]  = 0.4886025119029199f  * uy;
                Yf[2]  = 0.4886025119029199f  * uz;
                Yf[3]  = 0.4886025119029199f  * ux;
                Yf[4]  = 1.0925484305920792f  * ux * uy;
                Yf[5]  = 1.0925484305920792f  * uy * uz;
                Yf[6]  = 0.31539156525252005f * (3.0f*zz - 1.0f);
                Yf[7]  = 1.0925484305920792f  * ux * uz;
                Yf[8]  = 0.5462742152960396f  * (xx - yy);
                Yf[9]  = 0.5900435899266435f  * uy * (3.0f*xx - yy);
                Yf[10] = 2.890611442640554f   * ux * uy * uz;
                Yf[11] = 0.4570457994644658f  * uy * (5.0f*zz - 1.0f);
                Yf[12] = 0.3731763325901154f  * uz * (5.0f*zz - 3.0f);
                Yf[13] = 0.4570457994644658f  * ux * (5.0f*zz - 1.0f);
                Yf[14] = 1.445305721320277f   * uz * (xx - yy);
                Yf[15] = 0.5900435899266435f  * ux * (xx - 3.0f*yy);
            }

            int rb = node * 8;
            #pragma unroll
            for (int a = 0; a < 8; ++a) {
                sWRT[(rb + a) * TR + lane]       = wrh[a];
                sWRT[((rb ^ 8) + a) * TR + lane] = (_Float16)0.0f;
            }
            #pragma unroll
            for (int m = 0; m < 16; ++m) sYT[m * TR + lane] = (_Float16)Yf[m];
            wsync();

            acc = __builtin_amdgcn_mfma_f32_16x16x32_f16(
                *(const half8*)&sWRT[row * TR + quad * 8],
                *(const half8*)&sYT [row * TR + quad * 8], acc, 0, 0, 0);
            if (total - base > 32)
                acc = __builtin_amdgcn_mfma_f32_16x16x32_f16(
                    *(const half8*)&sWRT[row * TR + 32 + quad * 8],
                    *(const half8*)&sYT [row * TR + 32 + quad * 8], acc, 0, 0, 0);
            wsync();
        }

        // epilogue scratch aliases the dead MFMA operand region (per-wave)
        float* sA = (float*)sWRT;
        float* sP = sA + 256;

        #pragma unroll
        for (int rg = 0; rg < 4; ++rg)
            sA[(quad * 4 + rg) * 16 + row] = acc[rg];
        wsync();

        {   // P: all 64 lanes, one (node,a,l) each
            int nd = lane >> 5, a = (lane >> 2) & 7, l = lane & 3;
            int arow = nd * 8 + a;
            int m0 = l * l, m1 = (l + 1) * (l + 1);
            float s = 0.0f;
            for (int m = m0; m < m1; ++m) { float vv = sA[arow * 16 + m]; s += vv * vv; }
            sP[nd * 32 + a * 4 + l] = s;
        }
        wsync();

        int nd = lane >> 5, l32 = lane & 31;
        int n = nd ? n1 : n0;
        int z = nd ? z1 : z0;
        const float* sPn = sP + nd * 32;
        const floatx4* cr4 = (const floatx4*)(c_read + (size_t)z * NUM_BASIS);
        floatx4* Brow4 = (floatx4*)(outB + (size_t)n * NUM_BASIS);
        float Ep = 0.0f;
        #pragma unroll
        for (int it = 0; it < 8; ++it) {
            int fi = l32 + it * 32;
            if (fi < 232) {
                floatx4 B;
                if (fi < 8) {
                    B = *(const floatx4*)&sPn[fi * 4];
                } else {
                    int t = fi - 8;
                    int k = t % 7;
                    int t2 = t / 7;
                    int l = t2 & 3, a = t2 >> 2;
                    int o = k + (k >= a ? 1 : 0);
                    float pp = sPn[a * 4 + l];
                    floatx4 po = *(const floatx4*)&sPn[o * 4];
                    B = pp * po;
                }
                __builtin_nontemporal_store(B, &Brow4[fi]);
                floatx4 c = cr4[fi];
                Ep += B[0]*c[0] + B[1]*c[1] + B[2]*c[2] + B[3]*c[3];
            }
        }
        #pragma unroll
        for (int off = 16; off > 0; off >>= 1) Ep += __shfl_down(Ep, off);
        #pragma unroll
        for (int off = 1; off < 64; off <<= 1) {
            ep0 += __shfl_xor(ep0, off);
            ep1 += __shfl_xor(ep1, off);
        }
        if (l32 == 0) {
            float epv = nd ? ep1 : ep0;
            outE[n] = (Ep + epv + E0[z]) * node_mask[n];
        }
    }
}

// ===================== fallback path: exact CSR (unchanged) ==================
__global__ __launch_bounds__(256) void count_kernel(const int* __restrict__ receivers,
                                                    int* __restrict__ counts) {
    int e = blockIdx.x * blockDim.x + threadIdx.x;
    if (e < N_EDGES) atomicAdd(&counts[receivers[e]], 1);
}

__global__ __launch_bounds__(SCAN_B) void scan_blocks(const int* __restrict__ counts,
                                                      int* __restrict__ prefix,
                                                      int* __restrict__ blockSums) {
    int tid = threadIdx.x;
    int gid = blockIdx.x * SCAN_B + tid;
    int c = (gid < N_NODES) ? counts[gid] : 0;
    int lane = tid & 63, wave = tid >> 6;
    int s = c;
    #pragma unroll
    for (int off = 1; off < 64; off <<= 1) {
        int v = __shfl_up(s, off);
        if (lane >= off) s += v;
    }
    __shared__ int waveTot[16];
    __shared__ int waveExcl[16];
    if (lane == 63) waveTot[wave] = s;
    __syncthreads();
    if (tid == 0) {
        int run = 0;
        #pragma unroll
        for (int ww = 0; ww < 16; ++ww) { waveExcl[ww] = run; run += waveTot[ww]; }
        blockSums[blockIdx.x] = run;
    }
    __syncthreads();
    int excl = (s - c) + waveExcl[wave];
    if (gid < N_NODES) prefix[gid] = excl;
}

__global__ __launch_bounds__(SCAN_B) void scan_finalize(const int* __restrict__ prefix,
                                                        const int* __restrict__ blockSums,
                                                        int* __restrict__ offsets,
                                                        int* __restrict__ cursors) {
    __shared__ int blockOff;
    int tid = threadIdx.x;
    if (tid == 0) {
        int run = 0;
        for (int b = 0; b < blockIdx.x; ++b) run += blockSums[b];
        blockOff = run;
    }
    __syncthreads();
    int gid = blockIdx.x * SCAN_B + tid;
    if (gid < N_NODES) {
        int v = prefix[gid] + blockOff;
        offsets[gid] = v;
        cursors[gid] = v;
    }
}

__global__ __launch_bounds__(256) void scatter_rec_kernel(
    const float* __restrict__ vectors,
    const int* __restrict__ senders,
    const int* __restrict__ receivers,
    const int* __restrict__ species,
    int* __restrict__ cursors,
    float4* __restrict__ feat)
{
    int e = blockIdx.x * 256 + threadIdx.x;
    if (e >= N_EDGES) return;
    int rcv = receivers[e];
    int pos = atomicAdd(&cursors[rcv], 1);
    float4 rec;
    rec.x = vectors[3*e+0];
    rec.y = vectors[3*e+1];
    rec.z = vectors[3*e+2];
    rec.w = __int_as_float(species[senders[e]]);
    feat[pos] = rec;
}

// CSR-consuming node kernel (R7-verified), fallback only
__global__ __launch_bounds__(TPB, 5) void ace_node_csr(
    const float4* __restrict__ feat,
    const int* __restrict__ counts,
    const int* __restrict__ offsets,
    const int* __restrict__ species,
    const float* __restrict__ node_mask,
    const float* __restrict__ wA,
    const float* __restrict__ c_pair,
    const float* __restrict__ c_read,
    const float* __restrict__ E0,
    float* __restrict__ outE,
    float* __restrict__ outB)
{
    int tid = threadIdx.x;
    int w = tid >> 6, lane = tid & 63;
    int row = lane & 15, quad = lane >> 4;

    __shared__ __align__(16) _Float16 sOps[WPB][2][16 * TR];
    __shared__ float sWA[64];
    __shared__ float sCPall[512];

    if (tid < 64) sWA[tid] = wA[tid];
    sCPall[tid]       = c_pair[tid];
    sCPall[tid + 256] = c_pair[tid + 256];
    __syncthreads();

    _Float16* sWRT = &sOps[w][0][0];
    _Float16* sYT  = &sOps[w][1][0];

    int p = blockIdx.x * WPB + w;
    if (p >= NPAIRS) return;
    int n0 = p * 2, n1 = n0 + 1;
    int z0 = species[n0], z1 = species[n1];

    int c0 = counts[n0], c1 = counts[n1];
    size_t base0 = (size_t)offsets[n0], base1 = (size_t)offsets[n1];
    int total = c0 + c1;

    floatx4 acc = {0.0f, 0.0f, 0.0f, 0.0f};
    float ep0 = 0.0f, ep1 = 0.0f;

    for (int base = 0; base < total; base += 64) {
        int j = base + lane;
        bool active = j < total;
        int node = (j >= c0) ? 1 : 0;

        half8 wrh;
        #pragma unroll
        for (int a = 0; a < 8; ++a) wrh[a] = (_Float16)0.0f;
        float Yf[16];
        #pragma unroll
        for (int m = 0; m < 16; ++m) Yf[m] = 0.0f;

        if (active) {
            int jj = node ? (j - c0) : j;
            float4 rec = feat[(node ? base1 : base0) + jj];
            float vx = rec.x, vy = rec.y, vz = rec.z;
            int zs = __float_as_int(rec.w);

            float r2 = vx*vx + vy*vy + vz*vz + 1e-12f;
            float invr = rsqrtf(r2);
            float rr = r2 * invr;
            float dd = rr * 0.2f;
            float d2 = dd*dd, d6 = d2*d2*d2;
            float env = 1.0f + d6 * (-28.0f + 48.0f*dd - 21.0f*d2);
            env = (dd < 1.0f) ? env : 0.0f;
            float pref = 0.6324555320336759f * invr * env;

            float x = 3.14159265358979f * dd;
            float sp = __sinf(x), cp = __cosf(x);
            float twoc = 2.0f * cp;
            float Rn[NMAX];
            float s_prev = 0.0f, s_cur = sp;
            Rn[0] = pref * s_cur;
            #pragma unroll
            for (int nq = 1; nq < NMAX; ++nq) {
                float s_next = twoc * s_cur - s_prev;
                s_prev = s_cur; s_cur = s_next;
                Rn[nq] = pref * s_cur;
            }

            int zr = node ? z1 : z0;
            float ep = 0.0f;
            #pragma unroll
            for (int nq = 0; nq < NMAX; ++nq) ep += sCPall[(zr*8 + zs)*8 + nq] * Rn[nq];
            if (node) ep1 += 0.5f * ep; else ep0 += 0.5f * ep;

            #pragma unroll
            for (int a = 0; a < NMAX; ++a) wrh[a] = (_Float16)(sWA[zs*8+a] * Rn[a]);

            float ux = vx*invr, uy = vy*invr, uz = vz*invr;
            float xx = ux*ux, yy = uy*uy, zz = uz*uz;
            Yf[0]  = 0.28209479177387814f;
            Yf[1]  = 0.4886025119029199f  * uy;
            Yf[2]  = 0.4886025119029199f  * uz;
            Yf[3]  = 0.4886025119029199f  * ux;
            Yf[4]  = 1.0925484305920792f  * ux * uy;
            Yf[5]  = 1.0925484305920792f  * uy * uz;
            Yf[6]  = 0.31539156525252005f * (3.0f*zz - 1.0f);
            Yf[7]  = 1.0925484305920792f  * ux * uz;
            Yf[8]  = 0.5462742152960396f  * (xx - yy);
            Yf[9]  = 0.5900435899266435f  * uy * (3.0f*xx - yy);
            Yf[10] = 2.890611442640554f   * ux * uy * uz;
            Yf[11] = 0.4570457994644658f  * uy * (5.0f*zz - 1.0f);
            Yf[12] = 0.3731763325901154f  * uz * (5.0f*zz - 3.0f);
            Yf[13] = 0.4570457994644658f  * ux * (5.0f*zz - 1.0f);
            Yf[14] = 1.445305721320277f   * uz * (xx - yy);
            Yf[15] = 0.5900435899266435f  * ux * (xx - 3.0f*yy);
        }

        int rb = node * 8;
        #pragma unroll
        for (int a = 0; a < 8; ++a) {
            sWRT[(rb + a) * TR + lane]       = wrh[a];
            sWRT[((rb ^ 8) + a) * TR + lane] = (_Float16)0.0f;
        }
        #pragma unroll
        for (int m = 0; m < 16; ++m) sYT[m * TR + lane] = (_Float16)Yf[m];
        wsync();

        acc = __builtin_amdgcn_mfma_f32_16x16x32_f16(
            *(const half8*)&sWRT[row * TR + quad * 8],
            *(const half8*)&sYT [row * TR + quad * 8], acc, 0, 0, 0);
        if (total - base > 32)
            acc = __builtin_amdgcn_mfma_f32_16x16x32_f16(
                *(const half8*)&sWRT[row * TR + 32 + quad * 8],
                *(const half8*)&sYT [row * TR + 32 + quad * 8], acc, 0, 0, 0);
        wsync();
    }

    float* sA = (float*)sWRT;
    float* sP = sA + 256;

    #pragma unroll
    for (int rg = 0; rg < 4; ++rg)
        sA[(quad * 4 + rg) * 16 + row] = acc[rg];
    wsync();

    {
        int nd = lane >> 5, a = (lane >> 2) & 7, l = lane & 3;
        int arow = nd * 8 + a;
        int m0 = l * l, m1 = (l + 1) * (l + 1);
        float s = 0.0f;
        for (int m = m0; m < m1; ++m) { float vv = sA[arow * 16 + m]; s += vv * vv; }
        sP[nd * 32 + a * 4 + l] = s;
    }
    wsync();

    int nd = lane >> 5, l32 = lane & 31;
    int n = nd ? n1 : n0;
    int z = nd ? z1 : z0;
    const float* sPn = sP + nd * 32;
    const floatx4* cr4 = (const floatx4*)(c_read + (size_t)z * NUM_BASIS);
    floatx4* Brow4 = (floatx4*)(outB + (size_t)n * NUM_BASIS);
    float Ep = 0.0f;
    #pragma unroll
    for (int it = 0; it < 8; ++it) {
        int fi = l32 + it * 32;
        if (fi < 232) {
            floatx4 B;
            if (fi < 8) {
                B = *(const floatx4*)&sPn[fi * 4];
            } else {
                int t = fi - 8;
                int k = t % 7;
                int t2 = t / 7;
                int l = t2 & 3, a = t2 >> 2;
                int o = k + (k >= a ? 1 : 0);
                float pp = sPn[a * 4 + l];
                floatx4 po = *(const floatx4*)&sPn[o * 4];
                B = pp * po;
            }
            __builtin_nontemporal_store(B, &Brow4[fi]);
            floatx4 c = cr4[fi];
            Ep += B[0]*c[0] + B[1]*c[1] + B[2]*c[2] + B[3]*c[3];
        }
    }
    #pragma unroll
    for (int off = 16; off > 0; off >>= 1) Ep += __shfl_down(Ep, off);
    #pragma unroll
    for (int off = 1; off < 64; off <<= 1) {
        ep0 += __shfl_xor(ep0, off);
        ep1 += __shfl_xor(ep1, off);
    }
    if (l32 == 0) {
        float epv = nd ? ep1 : ep0;
        outE[n] = (Ep + epv + E0[z]) * node_mask[n];
    }
}

extern "C" void kernel_launch(void* const* d_in, const int* in_sizes, int n_in,
                              void* d_out, int out_size, void* d_ws, size_t ws_size,
                              hipStream_t stream) {
    const float* vectors   = (const float*)d_in[0];
    const int*   senders   = (const int*)d_in[1];
    const int*   receivers = (const int*)d_in[2];
    const int*   species   = (const int*)d_in[3];
    const float* node_mask = (const float*)d_in[4];
    const float* wA        = (const float*)d_in[5];
    const float* c_read    = (const float*)d_in[6];
    const float* E0        = (const float*)d_in[7];
    const float* c_pair    = (const float*)d_in[8];

    float* outE = (float*)d_out;        // [20000]
    float* outB = outE + N_NODES;       // [20000][928]

    size_t binnedBytes = (size_t)NRANGE * BINCAP * sizeof(float4);           // 12.29 MB
    size_t gcountBytes = (size_t)NBLK * NRANGE * sizeof(int);                // 256 KB
    size_t countBytes  = (size_t)NRANGE * sizeof(int);                       // 1 KB
    size_t primaryNeed = binnedBytes + gcountBytes + countBytes;             // ~12.6 MB

    if (ws_size >= primaryNeed) {
        // ---- primary: 4 dispatches, no memset, no global atomics,
        //      no random 64B line-touches ----
        float4* binned = (float4*)d_ws;
        int* gcounts   = (int*)((char*)d_ws + binnedBytes);
        int* counts    = (int*)((char*)d_ws + binnedBytes + gcountBytes);
        hist_kernel<<<NBLK, BINT, 0, stream>>>(receivers, gcounts);
        scan_bins<<<(NRANGE + 3)/4, 256, 0, stream>>>(gcounts, counts);
        bin_scatter<<<NBLK, BINT, 0, stream>>>(
            vectors, senders, receivers, species, gcounts, binned);
        range_compute<<<NRANGE, BINT, 0, stream>>>(
            binned, counts, species, node_mask, wA, c_pair, c_read, E0, outE, outB);
    } else {
        // ---- fallback: exact CSR of records (10.24 MB + scan arrays) ----
        float4* feat   = (float4*)d_ws;                    // 640000 recs
        int* counts    = (int*)((char*)d_ws + (size_t)N_EDGES * sizeof(float4));
        int* offsets   = counts + N_NODES;
        int* cursors   = offsets + N_NODES;
        int* prefix    = cursors + N_NODES;
        int* blockSums = prefix + N_NODES;
        hipMemsetAsync(counts, 0, N_NODES * sizeof(int), stream);
        count_kernel<<<(N_EDGES + 255)/256, 256, 0, stream>>>(receivers, counts);
        scan_blocks<<<SCAN_NB, SCAN_B, 0, stream>>>(counts, prefix, blockSums);
        scan_finalize<<<SCAN_NB, SCAN_B, 0, stream>>>(prefix, blockSums, offsets, cursors);
        scatter_rec_kernel<<<(N_EDGES + 255)/256, 256, 0, stream>>>(
            vectors, senders, receivers, species, cursors, feat);
        ace_node_csr<<<(NPAIRS + WPB - 1)/WPB, TPB, 0, stream>>>(
            feat, counts, offsets, species, node_mask,
            wA, c_pair, c_read, E0, outE, outB);
    }
}

// Round 12
// 135.804 us; speedup vs baseline: 1.2699x; 1.0270x over previous
//
#include <hip/hip_runtime.h>
#include <math.h>

#define N_NODES 20000
#define N_EDGES 640000
#define NMAX 8
#define NUM_BASIS 928
#define NRANGE 250        // coarse ranges (bins)
#define RNODES 80         // nodes per range; 250*80 = 20000
#define BINCAP 3072       // compacted records per bin; mean 2560, +10 sigma
#define SUBCAP 32         // stripe slots per (bin,block); Poisson(10), P(>32)~7e-9
#define TR 72             // f16 LDS row stride (k-dim), 144 B -> bank-spread
#define NBLK 256          // binning blocks
#define CHUNK (N_EDGES / NBLK)          // 2500
#define BINT 512          // threads per binning/compute block (8 waves)
#define TPB 256
#define WPB 4
#define NPAIRS (N_NODES / 2)
#define SCAN_B 1024
#define SCAN_NB ((N_NODES + SCAN_B - 1) / SCAN_B)   // 20

typedef _Float16 half8 __attribute__((ext_vector_type(8)));
typedef float floatx4 __attribute__((ext_vector_type(4)));

// wave-local LDS sync (guide rule #18)
__device__ __forceinline__ void wsync() {
    asm volatile("s_waitcnt lgkmcnt(0)" ::: "memory");
    __builtin_amdgcn_sched_barrier(0);
}

// ============== primary: TWO dispatches, stripe-direct range-binning =========
// R9/R11 established: no random 64B line-touches, no global atomics, no
// VGPR caps. R12: component arithmetic says kernels sum to ~27us of the ~90us
// we own -> dispatch gaps dominate. Cut 4 dispatches to 2 by giving each
// (bin,block) a private stripe: no hist pass, no scan pass, no global bases.

// dispatch 1: direct scatter into private stripes; zero global atomics,
// zero memset (counts written unconditionally), writes in ~10-slot runs.
__global__ __launch_bounds__(BINT) void bin_scatter_direct(
    const float* __restrict__ vectors,
    const int* __restrict__ senders,
    const int* __restrict__ receivers,
    const int* __restrict__ species,
    float4* __restrict__ binned,         // [NRANGE][NBLK][SUBCAP]
    int* __restrict__ counts)            // [NBLK][NRANGE]
{
    __shared__ int cur[NRANGE];
    int tid = threadIdx.x, b = blockIdx.x;
    for (int i = tid; i < NRANGE; i += BINT) cur[i] = 0;
    __syncthreads();
    int e0 = b * CHUNK;
    for (int i = tid; i < CHUNK; i += BINT) {
        int e = e0 + i;
        int rcv = receivers[e];
        int bin = rcv / RNODES;
        int nl  = rcv - bin * RNODES;                  // 0..79
        int pos = atomicAdd(&cur[bin], 1);             // LDS atomic only
        if (pos < SUBCAP) {
            int zs = species[senders[e]];              // 80KB table, L2-hot
            float4 rec;
            rec.x = vectors[3*e+0];
            rec.y = vectors[3*e+1];
            rec.z = vectors[3*e+2];
            rec.w = __int_as_float((zs << 7) | nl);
            binned[((size_t)bin * NBLK + b) * SUBCAP + pos] = rec;
        }
    }
    __syncthreads();
    for (int i = tid; i < NRANGE; i += BINT)
        counts[b * NRANGE + i] = min(cur[i], SUBCAP);  // coalesced
}

// dispatch 2: one block per range. Stripe-compact read (2 threads/stripe) ->
// LDS counting-sort by node (R11-verified) -> per-wave pair compute.
// launch_bounds(BINT,1): do NOT cap registers (R10 lesson: (BINT,2) spills).
__global__ __launch_bounds__(BINT, 1) void range_compute(
    const float4* __restrict__ binned,   // [NRANGE][NBLK][SUBCAP]
    const int* __restrict__ counts,      // [NBLK][NRANGE]
    const int* __restrict__ species,
    const float* __restrict__ node_mask,
    const float* __restrict__ wA,
    const float* __restrict__ c_pair,
    const float* __restrict__ c_read,
    const float* __restrict__ E0,
    float* __restrict__ outE,
    float* __restrict__ outB)
{
    __shared__ __align__(16) float4 sRec[BINCAP];               // 48 KB
    __shared__ __align__(16) _Float16 sOps[8][2][16 * TR];      // 36.9 KB
    __shared__ int sCnt[NBLK];                                  // 1 KB
    __shared__ int sHist[RNODES];
    __shared__ int sOff[RNODES + 1];
    __shared__ int sCur[RNODES];
    __shared__ float sWA[64];
    __shared__ float sCPall[512];

    int tid = threadIdx.x;
    int w = tid >> 6, lane = tid & 63;
    int row = lane & 15, quad = lane >> 4;
    int r = blockIdx.x;

    if (tid < 64) sWA[tid] = wA[tid];
    if (tid < 256) { sCPall[tid] = c_pair[tid]; sCPall[tid + 256] = c_pair[tid + 256]; }
    for (int i = tid; i < RNODES; i += BINT) sHist[i] = 0;
    if (tid < NBLK) sCnt[tid] = counts[tid * NRANGE + r];  // 256KB array, L2-hot
    __syncthreads();

    // phase A: histogram of node-local ids (2 threads per stripe)
    int st = tid >> 1, par = tid & 1;
    const float4* src = binned + ((size_t)r * NBLK + st) * SUBCAP;
    int sc = sCnt[st];
    for (int i = par; i < sc; i += 2)
        atomicAdd(&sHist[__float_as_int(src[i].w) & 127], 1);
    __syncthreads();
    if (tid == 0) {                       // 80-entry serial prefix (R11-proven)
        int run = 0;
        for (int i = 0; i < RNODES; ++i) { sOff[i] = run; run += sHist[i]; }
        sOff[RNODES] = run;
    }
    __syncthreads();
    for (int i = tid; i < RNODES; i += BINT) sCur[i] = sOff[i];
    __syncthreads();
    // phase B: scatter into node-grouped LDS (second read L2-hot; order within
    // node irrelevant: segment_sum is order-insensitive up to FP)
    for (int i = par; i < sc; i += 2) {
        float4 rec = src[i];
        int nl = __float_as_int(rec.w) & 127;
        int pos = atomicAdd(&sCur[nl], 1);
        if (pos < BINCAP) sRec[pos] = rec;
    }
    __syncthreads();

    _Float16* sWRT = &sOps[w][0][0];
    _Float16* sYT  = &sOps[w][1][0];

    // 40 pairs / 8 waves = 5 sequential pairs per wave
    for (int pi = w; pi < RNODES / 2; pi += 8) {
        wsync();                          // sWRT alias reuse across pairs
        int nl0 = pi * 2, nl1 = nl0 + 1;
        int n0 = r * RNODES + nl0, n1 = n0 + 1;
        int z0 = species[n0], z1 = species[n1];
        int b0 = sOff[nl0], b1 = sOff[nl1];
        int c0 = b1 - b0, c1 = sOff[nl1 + 1] - b1;
        int total = c0 + c1;

        floatx4 acc = {0.0f, 0.0f, 0.0f, 0.0f};
        float ep0 = 0.0f, ep1 = 0.0f;

        for (int base = 0; base < total; base += 64) {
            int j = base + lane;
            bool active = j < total;
            int node = (j >= c0) ? 1 : 0;

            half8 wrh;
            #pragma unroll
            for (int a = 0; a < 8; ++a) wrh[a] = (_Float16)0.0f;
            float Yf[16];
            #pragma unroll
            for (int m = 0; m < 16; ++m) Yf[m] = 0.0f;

            if (active) {
                int jj = node ? (j - c0) : j;
                float4 rec = sRec[(node ? b1 : b0) + jj];   // LDS, grouped
                float vx = rec.x, vy = rec.y, vz = rec.z;
                int zs = __float_as_int(rec.w) >> 7;

                float r2 = vx*vx + vy*vy + vz*vz + 1e-12f;
                float invr = rsqrtf(r2);
                float rr = r2 * invr;
                float dd = rr * 0.2f;                  // r / RCUT
                float d2 = dd*dd, d6 = d2*d2*d2;
                float env = 1.0f + d6 * (-28.0f + 48.0f*dd - 21.0f*d2);
                env = (dd < 1.0f) ? env : 0.0f;
                float pref = 0.6324555320336759f * invr * env;

                float x = 3.14159265358979f * dd;
                float sp = __sinf(x), cp = __cosf(x);
                float twoc = 2.0f * cp;
                float Rn[NMAX];
                float s_prev = 0.0f, s_cur = sp;
                Rn[0] = pref * s_cur;
                #pragma unroll
                for (int nq = 1; nq < NMAX; ++nq) {
                    float s_next = twoc * s_cur - s_prev;
                    s_prev = s_cur; s_cur = s_next;
                    Rn[nq] = pref * s_cur;
                }

                int zr = node ? z1 : z0;
                float ep = 0.0f;
                #pragma unroll
                for (int nq = 0; nq < NMAX; ++nq) ep += sCPall[(zr*8 + zs)*8 + nq] * Rn[nq];
                if (node) ep1 += 0.5f * ep; else ep0 += 0.5f * ep;

                #pragma unroll
                for (int a = 0; a < NMAX; ++a) wrh[a] = (_Float16)(sWA[zs*8+a] * Rn[a]);

                float ux = vx*invr, uy = vy*invr, uz = vz*invr;
                float xx = ux*ux, yy = uy*uy, zz = uz*uz;
                Yf[0]  = 0.28209479177387814f;
                Yf[1]  = 0.4886025119029199f  * uy;
                Yf[2]  = 0.4886025119029199f  * uz;
                Yf[3]  = 0.4886025119029199f  * ux;
                Yf[4]  = 1.0925484305920792f  * ux * uy;
                Yf[5]  = 1.0925484305920792f  * uy * uz;
                Yf[6]  = 0.31539156525252005f * (3.0f*zz - 1.0f);
                Yf[7]  = 1.0925484305920792f  * ux * uz;
                Yf[8]  = 0.5462742152960396f  * (xx - yy);
                Yf[9]  = 0.5900435899266435f  * uy * (3.0f*xx - yy);
                Yf[10] = 2.890611442640554f   * ux * uy * uz;
                Yf[11] = 0.4570457994644658f  * uy * (5.0f*zz - 1.0f);
                Yf[12] = 0.3731763325901154f  * uz * (5.0f*zz - 3.0f);
                Yf[13] = 0.4570457994644658f  * ux * (5.0f*zz - 1.0f);
                Yf[14] = 1.445305721320277f   * uz * (xx - yy);
                Yf[15] = 0.5900435899266435f  * ux * (xx - 3.0f*yy);
            }

            int rb = node * 8;
            #pragma unroll
            for (int a = 0; a < 8; ++a) {
                sWRT[(rb + a) * TR + lane]       = wrh[a];
                sWRT[((rb ^ 8) + a) * TR + lane] = (_Float16)0.0f;
            }
            #pragma unroll
            for (int m = 0; m < 16; ++m) sYT[m * TR + lane] = (_Float16)Yf[m];
            wsync();

            acc = __builtin_amdgcn_mfma_f32_16x16x32_f16(
                *(const half8*)&sWRT[row * TR + quad * 8],
                *(const half8*)&sYT [row * TR + quad * 8], acc, 0, 0, 0);
            if (total - base > 32)
                acc = __builtin_amdgcn_mfma_f32_16x16x32_f16(
                    *(const half8*)&sWRT[row * TR + 32 + quad * 8],
                    *(const half8*)&sYT [row * TR + 32 + quad * 8], acc, 0, 0, 0);
            wsync();
        }

        // epilogue scratch aliases the dead MFMA operand region (per-wave)
        float* sA = (float*)sWRT;
        float* sP = sA + 256;

        #pragma unroll
        for (int rg = 0; rg < 4; ++rg)
            sA[(quad * 4 + rg) * 16 + row] = acc[rg];
        wsync();

        {   // P: all 64 lanes, one (node,a,l) each
            int nd = lane >> 5, a = (lane >> 2) & 7, l = lane & 3;
            int arow = nd * 8 + a;
            int m0 = l * l, m1 = (l + 1) * (l + 1);
            float s = 0.0f;
            for (int m = m0; m < m1; ++m) { float vv = sA[arow * 16 + m]; s += vv * vv; }
            sP[nd * 32 + a * 4 + l] = s;
        }
        wsync();

        int nd = lane >> 5, l32 = lane & 31;
        int n = nd ? n1 : n0;
        int z = nd ? z1 : z0;
        const float* sPn = sP + nd * 32;
        const floatx4* cr4 = (const floatx4*)(c_read + (size_t)z * NUM_BASIS);
        floatx4* Brow4 = (floatx4*)(outB + (size_t)n * NUM_BASIS);
        float Ep = 0.0f;
        #pragma unroll
        for (int it = 0; it < 8; ++it) {
            int fi = l32 + it * 32;
            if (fi < 232) {
                floatx4 B;
                if (fi < 8) {
                    B = *(const floatx4*)&sPn[fi * 4];
                } else {
                    int t = fi - 8;
                    int k = t % 7;
                    int t2 = t / 7;
                    int l = t2 & 3, a = t2 >> 2;
                    int o = k + (k >= a ? 1 : 0);
                    float pp = sPn[a * 4 + l];
                    floatx4 po = *(const floatx4*)&sPn[o * 4];
                    B = pp * po;
                }
                __builtin_nontemporal_store(B, &Brow4[fi]);
                floatx4 c = cr4[fi];
                Ep += B[0]*c[0] + B[1]*c[1] + B[2]*c[2] + B[3]*c[3];
            }
        }
        #pragma unroll
        for (int off = 16; off > 0; off >>= 1) Ep += __shfl_down(Ep, off);
        #pragma unroll
        for (int off = 1; off < 64; off <<= 1) {
            ep0 += __shfl_xor(ep0, off);
            ep1 += __shfl_xor(ep1, off);
        }
        if (l32 == 0) {
            float epv = nd ? ep1 : ep0;
            outE[n] = (Ep + epv + E0[z]) * node_mask[n];
        }
    }
}

// ===================== fallback path: exact CSR (unchanged) ==================
__global__ __launch_bounds__(256) void count_kernel(const int* __restrict__ receivers,
                                                    int* __restrict__ counts) {
    int e = blockIdx.x * blockDim.x + threadIdx.x;
    if (e < N_EDGES) atomicAdd(&counts[receivers[e]], 1);
}

__global__ __launch_bounds__(SCAN_B) void scan_blocks(const int* __restrict__ counts,
                                                      int* __restrict__ prefix,
                                                      int* __restrict__ blockSums) {
    int tid = threadIdx.x;
    int gid = blockIdx.x * SCAN_B + tid;
    int c = (gid < N_NODES) ? counts[gid] : 0;
    int lane = tid & 63, wave = tid >> 6;
    int s = c;
    #pragma unroll
    for (int off = 1; off < 64; off <<= 1) {
        int v = __shfl_up(s, off);
        if (lane >= off) s += v;
    }
    __shared__ int waveTot[16];
    __shared__ int waveExcl[16];
    if (lane == 63) waveTot[wave] = s;
    __syncthreads();
    if (tid == 0) {
        int run = 0;
        #pragma unroll
        for (int ww = 0; ww < 16; ++ww) { waveExcl[ww] = run; run += waveTot[ww]; }
        blockSums[blockIdx.x] = run;
    }
    __syncthreads();
    int excl = (s - c) + waveExcl[wave];
    if (gid < N_NODES) prefix[gid] = excl;
}

__global__ __launch_bounds__(SCAN_B) void scan_finalize(const int* __restrict__ prefix,
                                                        const int* __restrict__ blockSums,
                                                        int* __restrict__ offsets,
                                                        int* __restrict__ cursors) {
    __shared__ int blockOff;
    int tid = threadIdx.x;
    if (tid == 0) {
        int run = 0;
        for (int b = 0; b < blockIdx.x; ++b) run += blockSums[b];
        blockOff = run;
    }
    __syncthreads();
    int gid = blockIdx.x * SCAN_B + tid;
    if (gid < N_NODES) {
        int v = prefix[gid] + blockOff;
        offsets[gid] = v;
        cursors[gid] = v;
    }
}

__global__ __launch_bounds__(256) void scatter_rec_kernel(
    const float* __restrict__ vectors,
    const int* __restrict__ senders,
    const int* __restrict__ receivers,
    const int* __restrict__ species,
    int* __restrict__ cursors,
    float4* __restrict__ feat)
{
    int e = blockIdx.x * 256 + threadIdx.x;
    if (e >= N_EDGES) return;
    int rcv = receivers[e];
    int pos = atomicAdd(&cursors[rcv], 1);
    float4 rec;
    rec.x = vectors[3*e+0];
    rec.y = vectors[3*e+1];
    rec.z = vectors[3*e+2];
    rec.w = __int_as_float(species[senders[e]]);
    feat[pos] = rec;
}

// CSR-consuming node kernel (R7-verified), fallback only
__global__ __launch_bounds__(TPB, 5) void ace_node_csr(
    const float4* __restrict__ feat,
    const int* __restrict__ counts,
    const int* __restrict__ offsets,
    const int* __restrict__ species,
    const float* __restrict__ node_mask,
    const float* __restrict__ wA,
    const float* __restrict__ c_pair,
    const float* __restrict__ c_read,
    const float* __restrict__ E0,
    float* __restrict__ outE,
    float* __restrict__ outB)
{
    int tid = threadIdx.x;
    int w = tid >> 6, lane = tid & 63;
    int row = lane & 15, quad = lane >> 4;

    __shared__ __align__(16) _Float16 sOps[WPB][2][16 * TR];
    __shared__ float sWA[64];
    __shared__ float sCPall[512];

    if (tid < 64) sWA[tid] = wA[tid];
    sCPall[tid]       = c_pair[tid];
    sCPall[tid + 256] = c_pair[tid + 256];
    __syncthreads();

    _Float16* sWRT = &sOps[w][0][0];
    _Float16* sYT  = &sOps[w][1][0];

    int p = blockIdx.x * WPB + w;
    if (p >= NPAIRS) return;
    int n0 = p * 2, n1 = n0 + 1;
    int z0 = species[n0], z1 = species[n1];

    int c0 = counts[n0], c1 = counts[n1];
    size_t base0 = (size_t)offsets[n0], base1 = (size_t)offsets[n1];
    int total = c0 + c1;

    floatx4 acc = {0.0f, 0.0f, 0.0f, 0.0f};
    float ep0 = 0.0f, ep1 = 0.0f;

    for (int base = 0; base < total; base += 64) {
        int j = base + lane;
        bool active = j < total;
        int node = (j >= c0) ? 1 : 0;

        half8 wrh;
        #pragma unroll
        for (int a = 0; a < 8; ++a) wrh[a] = (_Float16)0.0f;
        float Yf[16];
        #pragma unroll
        for (int m = 0; m < 16; ++m) Yf[m] = 0.0f;

        if (active) {
            int jj = node ? (j - c0) : j;
            float4 rec = feat[(node ? base1 : base0) + jj];
            float vx = rec.x, vy = rec.y, vz = rec.z;
            int zs = __float_as_int(rec.w);

            float r2 = vx*vx + vy*vy + vz*vz + 1e-12f;
            float invr = rsqrtf(r2);
            float rr = r2 * invr;
            float dd = rr * 0.2f;
            float d2 = dd*dd, d6 = d2*d2*d2;
            float env = 1.0f + d6 * (-28.0f + 48.0f*dd - 21.0f*d2);
            env = (dd < 1.0f) ? env : 0.0f;
            float pref = 0.6324555320336759f * invr * env;

            float x = 3.14159265358979f * dd;
            float sp = __sinf(x), cp = __cosf(x);
            float twoc = 2.0f * cp;
            float Rn[NMAX];
            float s_prev = 0.0f, s_cur = sp;
            Rn[0] = pref * s_cur;
            #pragma unroll
            for (int nq = 1; nq < NMAX; ++nq) {
                float s_next = twoc * s_cur - s_prev;
                s_prev = s_cur; s_cur = s_next;
                Rn[nq] = pref * s_cur;
            }

            int zr = node ? z1 : z0;
            float ep = 0.0f;
            #pragma unroll
            for (int nq = 0; nq < NMAX; ++nq) ep += sCPall[(zr*8 + zs)*8 + nq] * Rn[nq];
            if (node) ep1 += 0.5f * ep; else ep0 += 0.5f * ep;

            #pragma unroll
            for (int a = 0; a < NMAX; ++a) wrh[a] = (_Float16)(sWA[zs*8+a] * Rn[a]);

            float ux = vx*invr, uy = vy*invr, uz = vz*invr;
            float xx = ux*ux, yy = uy*uy, zz = uz*uz;
            Yf[0]  = 0.28209479177387814f;
            Yf[1]  = 0.4886025119029199f  * uy;
            Yf[2]  = 0.4886025119029199f  * uz;
            Yf[3]  = 0.4886025119029199f  * ux;
            Yf[4]  = 1.0925484305920792f  * ux * uy;
            Yf[5]  = 1.0925484305920792f  * uy * uz;
            Yf[6]  = 0.31539156525252005f * (3.0f*zz - 1.0f);
            Yf[7]  = 1.0925484305920792f  * ux * uz;
            Yf[8]  = 0.5462742152960396f  * (xx - yy);
            Yf[9]  = 0.5900435899266435f  * uy * (3.0f*xx - yy);
            Yf[10] = 2.890611442640554f   * ux * uy * uz;
            Yf[11] = 0.4570457994644658f  * uy * (5.0f*zz - 1.0f);
            Yf[12] = 0.3731763325901154f  * uz * (5.0f*zz - 3.0f);
            Yf[13] = 0.4570457994644658f  * ux * (5.0f*zz - 1.0f);
            Yf[14] = 1.445305721320277f   * uz * (xx - yy);
            Yf[15] = 0.5900435899266435f  * ux * (xx - 3.0f*yy);
        }

        int rb = node * 8;
        #pragma unroll
        for (int a = 0; a < 8; ++a) {
            sWRT[(rb + a) * TR + lane]       = wrh[a];
            sWRT[((rb ^ 8) + a) * TR + lane] = (_Float16)0.0f;
        }
        #pragma unroll
        for (int m = 0; m < 16; ++m) sYT[m * TR + lane] = (_Float16)Yf[m];
        wsync();

        acc = __builtin_amdgcn_mfma_f32_16x16x32_f16(
            *(const half8*)&sWRT[row * TR + quad * 8],
            *(const half8*)&sYT [row * TR + quad * 8], acc, 0, 0, 0);
        if (total - base > 32)
            acc = __builtin_amdgcn_mfma_f32_16x16x32_f16(
                *(const half8*)&sWRT[row * TR + 32 + quad * 8],
                *(const half8*)&sYT [row * TR + 32 + quad * 8], acc, 0, 0, 0);
        wsync();
    }

    float* sA = (float*)sWRT;
    float* sP = sA + 256;

    #pragma unroll
    for (int rg = 0; rg < 4; ++rg)
        sA[(quad * 4 + rg) * 16 + row] = acc[rg];
    wsync();

    {
        int nd = lane >> 5, a = (lane >> 2) & 7, l = lane & 3;
        int arow = nd * 8 + a;
        int m0 = l * l, m1 = (l + 1) * (l + 1);
        float s = 0.0f;
        for (int m = m0; m < m1; ++m) { float vv = sA[arow * 16 + m]; s += vv * vv; }
        sP[nd * 32 + a * 4 + l] = s;
    }
    wsync();

    int nd = lane >> 5, l32 = lane & 31;
    int n = nd ? n1 : n0;
    int z = nd ? z1 : z0;
    const float* sPn = sP + nd * 32;
    const floatx4* cr4 = (const floatx4*)(c_read + (size_t)z * NUM_BASIS);
    floatx4* Brow4 = (floatx4*)(outB + (size_t)n * NUM_BASIS);
    float Ep = 0.0f;
    #pragma unroll
    for (int it = 0; it < 8; ++it) {
        int fi = l32 + it * 32;
        if (fi < 232) {
            floatx4 B;
            if (fi < 8) {
                B = *(const floatx4*)&sPn[fi * 4];
            } else {
                int t = fi - 8;
                int k = t % 7;
                int t2 = t / 7;
                int l = t2 & 3, a = t2 >> 2;
                int o = k + (k >= a ? 1 : 0);
                float pp = sPn[a * 4 + l];
                floatx4 po = *(const floatx4*)&sPn[o * 4];
                B = pp * po;
            }
            __builtin_nontemporal_store(B, &Brow4[fi]);
            floatx4 c = cr4[fi];
            Ep += B[0]*c[0] + B[1]*c[1] + B[2]*c[2] + B[3]*c[3];
        }
    }
    #pragma unroll
    for (int off = 16; off > 0; off >>= 1) Ep += __shfl_down(Ep, off);
    #pragma unroll
    for (int off = 1; off < 64; off <<= 1) {
        ep0 += __shfl_xor(ep0, off);
        ep1 += __shfl_xor(ep1, off);
    }
    if (l32 == 0) {
        float epv = nd ? ep1 : ep0;
        outE[n] = (Ep + epv + E0[z]) * node_mask[n];
    }
}

extern "C" void kernel_launch(void* const* d_in, const int* in_sizes, int n_in,
                              void* d_out, int out_size, void* d_ws, size_t ws_size,
                              hipStream_t stream) {
    const float* vectors   = (const float*)d_in[0];
    const int*   senders   = (const int*)d_in[1];
    const int*   receivers = (const int*)d_in[2];
    const int*   species   = (const int*)d_in[3];
    const float* node_mask = (const float*)d_in[4];
    const float* wA        = (const float*)d_in[5];
    const float* c_read    = (const float*)d_in[6];
    const float* E0        = (const float*)d_in[7];
    const float* c_pair    = (const float*)d_in[8];

    float* outE = (float*)d_out;        // [20000]
    float* outB = outE + N_NODES;       // [20000][928]

    size_t binnedBytes = (size_t)NRANGE * NBLK * SUBCAP * sizeof(float4);    // 32.77 MB
    size_t countBytes  = (size_t)NBLK * NRANGE * sizeof(int);                // 256 KB
    size_t primaryNeed = binnedBytes + countBytes;                           // ~33 MB

    if (ws_size >= primaryNeed) {
        // ---- primary: TWO dispatches, no memset, no global atomics,
        //      no random 64B line-touches ----
        float4* binned = (float4*)d_ws;
        int* counts    = (int*)((char*)d_ws + binnedBytes);
        bin_scatter_direct<<<NBLK, BINT, 0, stream>>>(
            vectors, senders, receivers, species, binned, counts);
        range_compute<<<NRANGE, BINT, 0, stream>>>(
            binned, counts, species, node_mask, wA, c_pair, c_read, E0, outE, outB);
    } else {
        // ---- fallback: exact CSR of records (10.24 MB + scan arrays) ----
        float4* feat   = (float4*)d_ws;                    // 640000 recs
        int* counts    = (int*)((char*)d_ws + (size_t)N_EDGES * sizeof(float4));
        int* offsets   = counts + N_NODES;
        int* cursors   = offsets + N_NODES;
        int* prefix    = cursors + N_NODES;
        int* blockSums = prefix + N_NODES;
        hipMemsetAsync(counts, 0, N_NODES * sizeof(int), stream);
        count_kernel<<<(N_EDGES + 255)/256, 256, 0, stream>>>(receivers, counts);
        scan_blocks<<<SCAN_NB, SCAN_B, 0, stream>>>(counts, prefix, blockSums);
        scan_finalize<<<SCAN_NB, SCAN_B, 0, stream>>>(prefix, blockSums, offsets, cursors);
        scatter_rec_kernel<<<(N_EDGES + 255)/256, 256, 0, stream>>>(
            vectors, senders, receivers, species, cursors, feat);
        ace_node_csr<<<(NPAIRS + WPB - 1)/WPB, TPB, 0, stream>>>(
            feat, counts, offsets, species, node_mask,
            wA, c_pair, c_read, E0, outE, outB);
    }
}